// Round 3
// baseline (220.698 us; speedup 1.0000x reference)
//
#include <hip/hip_runtime.h>
#include <stdint.h>

#define NGC 4096   // both node counts
#define FIN 512
#define DD  256

typedef __attribute__((ext_vector_type(8))) short short8;
typedef __attribute__((ext_vector_type(4))) float f32x4;
typedef unsigned short u16;
typedef unsigned int   u32;
typedef unsigned long long u64;

static __device__ __forceinline__ float bf2f(u16 u){ return __uint_as_float(((u32)u)<<16); }
static __device__ __forceinline__ u16 f2bf(float f){
  u32 u = __float_as_uint(f);
  u += 0x7fffu + ((u>>16)&1u);
  return (u16)(u>>16);
}
static __device__ __forceinline__ float lk(float x){ return fmaxf(x, 0.2f*x); }

// ---------------------------------------------------------------------------
// k_wcvt: W (f32) -> bf16 copies for the GEMM.
// ---------------------------------------------------------------------------
__global__ __launch_bounds__(256) void k_wcvt(
    const float* __restrict__ Wg, const float* __restrict__ Wc,
    u16* __restrict__ Wgbf, u16* __restrict__ Wcbf)
{
  int base = (blockIdx.x*256 + threadIdx.x)*4;   // grid 128 -> 131072 elems
  float4 a = *(const float4*)(Wg + base);
  float4 b = *(const float4*)(Wc + base);
  ushort4 oa, ob;
  oa.x=f2bf(a.x); oa.y=f2bf(a.y); oa.z=f2bf(a.z); oa.w=f2bf(a.w);
  ob.x=f2bf(b.x); ob.y=f2bf(b.y); ob.z=f2bf(b.z); ob.w=f2bf(b.w);
  *(ushort4*)(Wgbf + base) = oa;
  *(ushort4*)(Wcbf + base) = ob;
}

// ---------------------------------------------------------------------------
// k_hgemm: h = x @ W.T  (f32 x in -> bf16 staged, f32 h out + bf16 hT out)
// grid (64 row-tiles, 2 sides), 512 threads (8 waves). BM=64, BK=64, N=256.
// ---------------------------------------------------------------------------
__global__ __launch_bounds__(512) void k_hgemm(
    const float* __restrict__ xg, const float* __restrict__ xc,
    const u16* __restrict__ Wg, const u16* __restrict__ Wc,
    float* __restrict__ hg, float* __restrict__ hc,
    u16* __restrict__ hTg, u16* __restrict__ hTc)
{
  const int side = blockIdx.y;
  const float* x = side ? xc : xg;
  const u16* W = side ? Wc : Wg;
  float* h  = side ? hc : hg;
  u16*  hT  = side ? hTc : hTg;
  const int r0 = blockIdx.x * 64;
  const int t = threadIdx.x;
  const int wid = t >> 6, lane = t & 63;
  const int lrow = lane & 15, lhi = lane >> 4;

  __shared__ __align__(16) char smem[32768];

  f32x4 acc[4][2];
  const f32x4 z4 = {0.f,0.f,0.f,0.f};
  #pragma unroll
  for(int i=0;i<4;i++){ acc[i][0]=z4; acc[i][1]=z4; }

  const int r = t >> 3, c8 = t & 7;
  for(int k0 = 0; k0 < FIN; k0 += 64){
    const float* xp = x + (size_t)(r0 + r)*FIN + k0 + c8*8;
    float4 xa = *(const float4*)xp;
    float4 xb = *(const float4*)(xp + 4);
    short8 xv;
    xv[0]=(short)f2bf(xa.x); xv[1]=(short)f2bf(xa.y);
    xv[2]=(short)f2bf(xa.z); xv[3]=(short)f2bf(xa.w);
    xv[4]=(short)f2bf(xb.x); xv[5]=(short)f2bf(xb.y);
    xv[6]=(short)f2bf(xb.z); xv[7]=(short)f2bf(xb.w);
    int wbyte = r*128 + (((c8 ^ (r & 7)) & 7) << 4);
    *(short8*)(smem + wbyte) = xv;
    __syncthreads();
    #pragma unroll
    for(int ksub = 0; ksub < 2; ksub++){
      short8 b[2];
      #pragma unroll
      for(int nf=0; nf<2; nf++){
        int n = wid*32 + nf*16 + lrow;
        b[nf] = *(const short8*)(W + (size_t)n*FIN + k0 + ksub*32 + lhi*8);
      }
      #pragma unroll
      for(int mf=0; mf<4; mf++){
        int row = mf*16 + lrow;
        int g = ksub*4 + lhi;
        short8 a = *(const short8*)(smem + row*128 + (((g ^ (row & 7)) & 7) << 4));
        #pragma unroll
        for(int nf=0; nf<2; nf++)
          acc[mf][nf] = __builtin_amdgcn_mfma_f32_16x16x32_bf16(a, b[nf], acc[mf][nf], 0,0,0);
      }
    }
    __syncthreads();
  }
  // write h (f32) and stage bf16 transpose in LDS
  #pragma unroll
  for(int mf=0; mf<4; mf++){
    #pragma unroll
    for(int nf=0; nf<2; nf++){
      int col = wid*32 + nf*16 + lrow;
      #pragma unroll
      for(int j=0;j<4;j++){
        int row = mf*16 + lhi*4 + j;
        float v = acc[mf][nf][j];
        h[(size_t)(r0+row)*DD + col] = v;
        int byte_ = col*128 + (((row*2) ^ ((col & 7)<<4)));
        *(u16*)(smem + byte_) = f2bf(v);
      }
    }
  }
  __syncthreads();
  { // coalesced hT store: thread -> (n = t>>1, half = t&1)
    int n = t >> 1, half = t & 1;
    #pragma unroll
    for(int gi=0; gi<4; gi++){
      int g = half*4 + gi;
      int byte_ = n*128 + (((g ^ (n & 7)) & 7) << 4);
      short8 v = *(const short8*)(smem + byte_);
      *(short8*)(hT + (size_t)n*NGC + r0 + g*8) = v;
    }
  }
}

// ---------------------------------------------------------------------------
// k_svec: per-row dot products with attention vectors + gate sigmoid.
// sbuf layout (each 4096 f32):
// 0 s1gg 1 s2gg 2 s1gc 3 s2cg 4 gam_g 5 s1cc 6 s2cc 7 s2gc 8 s1cg 9 gam_c
// ---------------------------------------------------------------------------
__global__ __launch_bounds__(256) void k_svec(
    const float* __restrict__ hg, const float* __restrict__ hc,
    const float* __restrict__ a_gg, const float* __restrict__ a_gc,
    const float* __restrict__ a_cc, const float* __restrict__ a_cg,
    const float* __restrict__ gw_g, const float* __restrict__ gb_g,
    const float* __restrict__ gw_c, const float* __restrict__ gb_c,
    float* __restrict__ sbuf)
{
  int t = threadIdx.x, wid = t>>6, lane = t&63;
  int idx = blockIdx.x * 4 + wid;          // 0..8191
  int side = idx >> 12;
  int row  = idx & 4095;
  const float* h = (side ? hc : hg) + (size_t)row*DD;
  const float* v0 = (side ? a_cc : a_gg);        // same-type s1 half
  const float* v1 = (side ? a_cc : a_gg) + DD;   // same-type s2 half
  const float* v2 = (side ? a_cg : a_gc);        // cross s1 (this node as src)
  const float* v3 = (side ? a_gc : a_cg) + DD;   // cross s2 (this node as dst)
  const float* gw = side ? gw_c : gw_g;
  float bias = (side ? gb_c : gb_g)[0];

  float4 hv = *(const float4*)(h + lane*4);
  float4 w0 = *(const float4*)(v0 + lane*4);
  float4 w1 = *(const float4*)(v1 + lane*4);
  float4 w2 = *(const float4*)(v2 + lane*4);
  float4 w3 = *(const float4*)(v3 + lane*4);
  float4 w4 = *(const float4*)(gw + lane*4);

  float d0 = hv.x*w0.x + hv.y*w0.y + hv.z*w0.z + hv.w*w0.w;
  float d1 = hv.x*w1.x + hv.y*w1.y + hv.z*w1.z + hv.w*w1.w;
  float d2 = hv.x*w2.x + hv.y*w2.y + hv.z*w2.z + hv.w*w2.w;
  float d3 = hv.x*w3.x + hv.y*w3.y + hv.z*w3.z + hv.w*w3.w;
  float d4 = hv.x*w4.x + hv.y*w4.y + hv.z*w4.z + hv.w*w4.w;
  #pragma unroll
  for(int s=1;s<64;s<<=1){
    d0 += __shfl_xor(d0, s); d1 += __shfl_xor(d1, s); d2 += __shfl_xor(d2, s);
    d3 += __shfl_xor(d3, s); d4 += __shfl_xor(d4, s);
  }
  if(lane == 0){
    float gam = 1.f/(1.f + __expf(-(d4 + bias)));
    if(side == 0){
      sbuf[0*4096+row]=d0; sbuf[1*4096+row]=d1; sbuf[2*4096+row]=d2;
      sbuf[3*4096+row]=d3; sbuf[4*4096+row]=gam;
    } else {
      sbuf[5*4096+row]=d0; sbuf[6*4096+row]=d1; sbuf[8*4096+row]=d2;
      sbuf[7*4096+row]=d3; sbuf[9*4096+row]=gam;
    }
  }
}

// ---------------------------------------------------------------------------
// k_max: global max of the 4 "s2" arrays (one wave each). grid 1 x 256thr.
// ---------------------------------------------------------------------------
__global__ __launch_bounds__(256) void k_max(const float* __restrict__ sbuf,
                                             float* __restrict__ mx)
{
  int t = threadIdx.x, wid = t>>6, lane = t&63;
  const int offs[4] = {1,7,6,3};  // s2gg, s2gc(cell), s2cc, s2cg(gene)
  const float* a = sbuf + offs[wid]*4096;
  float m = -1e30f;
  for(int i = lane; i < 4096; i += 64) m = fmaxf(m, a[i]);
  #pragma unroll
  for(int s=1;s<64;s<<=1) m = fmaxf(m, __shfl_xor(m, s));
  if(lane==0) mx[wid] = m;
}

// ---------------------------------------------------------------------------
// k_bitT: bit-pack transpose of gene_cell_adj -> bitsT[c][g/64] (u64).
// grid (64 c-tiles, 4 g-quarters), 256 threads.
// ---------------------------------------------------------------------------
__global__ __launch_bounds__(256) void k_bitT(const float* __restrict__ adj,
                                              u64* __restrict__ bitsT)
{
  __shared__ u64 buf[64][17];
  int t = threadIdx.x, wid = t>>6, lane = t&63;
  int c0 = blockIdx.x * 64;
  int gbase = blockIdx.y * 1024;
  for(int g0 = 0; g0 < 1024; g0 += 64){
    for(int cc = 0; cc < 16; cc++){
      int cl = wid*16 + cc;
      float v = adj[(size_t)(gbase + g0 + lane)*NGC + c0 + cl];
      u64 mball = __ballot(v != 0.0f);
      if(lane == 0) buf[cl][g0>>6] = mball;
    }
  }
  __syncthreads();
  int c = t>>2, q = t&3;
  // row stride in bitsT is 64 u64; this block's g-quarter starts at u64
  // offset gbase>>6 (== blockIdx.y*16) within the row.
  u64* dst = bitsT + (size_t)(c0+c)*64 + (gbase>>6) + q*4;
  #pragma unroll
  for(int i=0;i<4;i++) dst[i] = buf[c][q*4+i];
}

// ---------------------------------------------------------------------------
// k_gat: one masked-softmax attention block per blockIdx.y mode.
// grid (64 row-tiles, 4 modes), 512 threads (8 waves).
// BM=64 src rows, BK=64 dst cols per step, D=256 split 8 waves x 32.
// m_i = leaky(s1_i + max_j s2_j) upper-bounds all logits -> no online rescale.
// ---------------------------------------------------------------------------
__global__ __launch_bounds__(512) void k_gat(
    const float* __restrict__ sbuf, const float* __restrict__ mx,
    const float* __restrict__ gene_adj, const float* __restrict__ cell_adj,
    const float* __restrict__ gc_adj,   const u64* __restrict__ bitsT,
    const u16* __restrict__ hTg, const u16* __restrict__ hTc,
    float* __restrict__ blk)
{
  const int mode = blockIdx.y;
  const float* s1; const float* s2; const float* adj = nullptr;
  const u16* vT; float* outp; const uint8_t* bits = nullptr;
  if(mode == 0){ s1 = sbuf+0*4096; s2 = sbuf+1*4096; adj = gene_adj; vT = hTg; outp = blk; }
  else if(mode == 1){ s1 = sbuf+2*4096; s2 = sbuf+7*4096; adj = gc_adj; vT = hTc; outp = blk + 1048576; }
  else if(mode == 2){ s1 = sbuf+5*4096; s2 = sbuf+6*4096; adj = cell_adj; vT = hTc; outp = blk + 2097152; }
  else { s1 = sbuf+8*4096; s2 = sbuf+3*4096; bits = (const uint8_t*)bitsT; vT = hTg; outp = blk + 3145728; }

  const float maxs2 = mx[mode];
  const int r0 = blockIdx.x * 64;
  const int t = threadIdx.x;
  const int wid = t>>6, lane = t&63, lrow = lane&15, lhi = lane>>4;
  const int r = t>>3, c8 = t&7;
  const int srow = r0 + r;

  __shared__ __align__(16) char psmem[8192];   // P tile [64][64] bf16, swizzled
  __shared__ float zbuf[64];

  const float s1v = s1[srow];
  const float m = lk(s1v + maxs2);
  float zacc = 0.f;
  const f32x4 z4 = {0.f,0.f,0.f,0.f};
  f32x4 acc[4][2];
  #pragma unroll
  for(int i=0;i<4;i++){ acc[i][0]=z4; acc[i][1]=z4; }
  const int n0 = wid*32;
  const bool useBits = (mode == 3);

  // prefetch first chunk
  float4 av0 = {0,0,0,0}, av1 = {0,0,0,0}; u32 ob = 0;
  if(useBits) ob = bits[(size_t)srow*512 + c8];
  else { const float* ap = adj + (size_t)srow*NGC + c8*8;
         av0 = *(const float4*)ap; av1 = *(const float4*)(ap+4); }
  float4 s2a = *(const float4*)(s2 + c8*8);
  float4 s2b = *(const float4*)(s2 + c8*8 + 4);

  for(int ks = 0; ks < 64; ks++){
    const int k0 = ks*64;
    float4 ca0 = av0, ca1 = av1; u32 obc = ob; float4 ca = s2a, cb = s2b;
    if(ks < 63){
      int k1 = k0 + 64;
      if(useBits) ob = bits[(size_t)srow*512 + (k1>>3) + c8];
      else { const float* ap = adj + (size_t)srow*NGC + k1 + c8*8;
             av0 = *(const float4*)ap; av1 = *(const float4*)(ap+4); }
      s2a = *(const float4*)(s2 + k1 + c8*8);
      s2b = *(const float4*)(s2 + k1 + c8*8 + 4);
    }
    // ---- p generation ----
    float s2v[8] = {ca.x,ca.y,ca.z,ca.w,cb.x,cb.y,cb.z,cb.w};
    float wv[8]  = {ca0.x,ca0.y,ca0.z,ca0.w,ca1.x,ca1.y,ca1.z,ca1.w};
    short8 pw;
    #pragma unroll
    for(int j=0;j<8;j++){
      float wj;
      if(useBits) wj = (float)((obc>>j)&1u);
      else        wj = wv[j];
      float p = wj * __expf(lk(s1v + s2v[j]) - m);
      zacc += p;
      pw[j] = (short)f2bf(p);
    }
    int wbyte = r*128 + (((c8 ^ (r&7)) & 7) << 4);
    *(short8*)(psmem + wbyte) = pw;
    __syncthreads();
    // ---- MFMA ----
    #pragma unroll
    for(int ksub=0; ksub<2; ksub++){
      short8 b[2];
      #pragma unroll
      for(int nf=0; nf<2; nf++){
        int n = n0 + nf*16 + lrow;
        b[nf] = *(const short8*)(vT + (size_t)n*NGC + k0 + ksub*32 + lhi*8);
      }
      #pragma unroll
      for(int mf=0; mf<4; mf++){
        int row = mf*16 + lrow;
        int g = ksub*4 + lhi;
        short8 a = *(const short8*)(psmem + row*128 + (((g ^ (row&7)) & 7) << 4));
        #pragma unroll
        for(int nf=0; nf<2; nf++)
          acc[mf][nf] = __builtin_amdgcn_mfma_f32_16x16x32_bf16(a, b[nf], acc[mf][nf], 0,0,0);
      }
    }
    __syncthreads();
  }
  // ---- Z reduction (8 threads per row are adjacent lanes) ----
  float z = zacc;
  z += __shfl_xor(z, 1);
  z += __shfl_xor(z, 2);
  z += __shfl_xor(z, 4);
  if(c8 == 0) zbuf[r] = z;
  __syncthreads();
  // ---- normalize + store ----
  #pragma unroll
  for(int mf=0; mf<4; mf++){
    #pragma unroll
    for(int j=0;j<4;j++){
      int row = mf*16 + lhi*4 + j;
      float rz = 1.f / fmaxf(zbuf[row], 1e-30f);
      #pragma unroll
      for(int nf=0; nf<2; nf++){
        int col = n0 + nf*16 + lrow;
        outp[(size_t)(r0+row)*DD + col] = acc[mf][nf][j] * rz;
      }
    }
  }
}

// ---------------------------------------------------------------------------
// k_epi: out = leaky(h + same + gamma*cross) for both sides.
// ---------------------------------------------------------------------------
__global__ __launch_bounds__(256) void k_epi(
    const float* __restrict__ hg, const float* __restrict__ hc,
    const float* __restrict__ blk, const float* __restrict__ sbuf,
    float* __restrict__ out)
{
  int i = blockIdx.x*256 + threadIdx.x;
  int base = i*4;
  int row = base >> 8;
  float gg = sbuf[4*4096 + row];
  float4 h4 = *(const float4*)(hg + base);
  float4 a4 = *(const float4*)(blk + base);
  float4 b4 = *(const float4*)(blk + 1048576 + base);
  float4 o;
  o.x = lk(h4.x + a4.x + gg*b4.x);
  o.y = lk(h4.y + a4.y + gg*b4.y);
  o.z = lk(h4.z + a4.z + gg*b4.z);
  o.w = lk(h4.w + a4.w + gg*b4.w);
  *(float4*)(out + base) = o;

  float gc = sbuf[9*4096 + row];
  float4 h4c = *(const float4*)(hc + base);
  float4 c4 = *(const float4*)(blk + 2097152 + base);
  float4 d4 = *(const float4*)(blk + 3145728 + base);
  float4 o2;
  o2.x = lk(h4c.x + c4.x + gc*d4.x);
  o2.y = lk(h4c.y + c4.y + gc*d4.y);
  o2.z = lk(h4c.z + c4.z + gc*d4.z);
  o2.w = lk(h4c.w + c4.w + gc*d4.w);
  *(float4*)(out + 1048576 + base) = o2;
}

// ---------------------------------------------------------------------------
extern "C" void kernel_launch(void* const* d_in, const int* in_sizes, int n_in,
                              void* d_out, int out_size, void* d_ws, size_t ws_size,
                              hipStream_t stream)
{
  const float* gene_x   = (const float*)d_in[0];
  const float* cell_x   = (const float*)d_in[1];
  const float* gene_adj = (const float*)d_in[2];
  const float* cell_adj = (const float*)d_in[3];
  const float* gc_adj   = (const float*)d_in[4];
  const float* Wg       = (const float*)d_in[5];
  const float* Wc       = (const float*)d_in[6];
  const float* a_gg     = (const float*)d_in[7];
  const float* a_gc     = (const float*)d_in[8];
  const float* a_cc     = (const float*)d_in[9];
  const float* a_cg     = (const float*)d_in[10];
  const float* gw_g     = (const float*)d_in[11];
  const float* gb_g     = (const float*)d_in[12];
  const float* gw_c     = (const float*)d_in[13];
  const float* gb_c     = (const float*)d_in[14];

  char* ws = (char*)d_ws;
  float* hg   = (float*)(ws);
  float* hc   = (float*)(ws + (4u<<20));
  u16*   hTg  = (u16*)  (ws + (8u<<20));
  u16*   hTc  = (u16*)  (ws + (10u<<20));
  float* sbuf = (float*)(ws + (12u<<20));
  float* mx   = (float*)(ws + (12u<<20) + (256u<<10));
  u64*   bitsT= (u64*)  (ws + (13u<<20));
  u16*   Wgbf = (u16*)  (ws + (15u<<20));
  u16*   Wcbf = (u16*)  (ws + (15u<<20) + (512u<<10));
  float* blk  = (float*)(ws + (16u<<20));

  k_wcvt<<<dim3(128), 256, 0, stream>>>(Wg, Wc, Wgbf, Wcbf);
  k_hgemm<<<dim3(64,2), 512, 0, stream>>>(gene_x, cell_x, Wgbf, Wcbf, hg, hc, hTg, hTc);
  k_svec<<<dim3(2048), 256, 0, stream>>>(hg, hc, a_gg, a_gc, a_cc, a_cg,
                                         gw_g, gb_g, gw_c, gb_c, sbuf);
  k_max<<<dim3(1), 256, 0, stream>>>(sbuf, mx);
  k_bitT<<<dim3(64,4), 256, 0, stream>>>(gc_adj, bitsT);
  k_gat<<<dim3(64,4), 512, 0, stream>>>(sbuf, mx, gene_adj, cell_adj, gc_adj,
                                        bitsT, hTg, hTc, blk);
  k_epi<<<dim3(1024), 256, 0, stream>>>(hg, hc, blk, sbuf, (float*)d_out);
}

// Round 4
// 208.377 us; speedup vs baseline: 1.0591x; 1.0591x over previous
//
#include <hip/hip_runtime.h>
#include <stdint.h>

#define NGC 4096   // both node counts
#define FIN 512
#define DD  256

typedef __attribute__((ext_vector_type(8))) short short8;
typedef __attribute__((ext_vector_type(4))) float f32x4;
typedef unsigned short u16;
typedef unsigned int   u32;
typedef unsigned long long u64;

static __device__ __forceinline__ float bf2f(u16 u){ return __uint_as_float(((u32)u)<<16); }
static __device__ __forceinline__ u16 f2bf(float f){
  u32 u = __float_as_uint(f);
  u += 0x7fffu + ((u>>16)&1u);
  return (u16)(u>>16);
}
static __device__ __forceinline__ float lk(float x){ return fmaxf(x, 0.2f*x); }
static __device__ __forceinline__ u64 shfl_xor64(u64 x, int m){
  u32 lo = (u32)x, hi = (u32)(x >> 32);
  lo = __shfl_xor(lo, m); hi = __shfl_xor(hi, m);
  return ((u64)hi << 32) | lo;
}

// ---------------------------------------------------------------------------
// k_wcvt: W (f32) -> bf16 copies for the GEMM.
// ---------------------------------------------------------------------------
__global__ __launch_bounds__(256) void k_wcvt(
    const float* __restrict__ Wg, const float* __restrict__ Wc,
    u16* __restrict__ Wgbf, u16* __restrict__ Wcbf)
{
  int base = (blockIdx.x*256 + threadIdx.x)*4;   // grid 128 -> 131072 elems
  float4 a = *(const float4*)(Wg + base);
  float4 b = *(const float4*)(Wc + base);
  ushort4 oa, ob;
  oa.x=f2bf(a.x); oa.y=f2bf(a.y); oa.z=f2bf(a.z); oa.w=f2bf(a.w);
  ob.x=f2bf(b.x); ob.y=f2bf(b.y); ob.z=f2bf(b.z); ob.w=f2bf(b.w);
  *(ushort4*)(Wgbf + base) = oa;
  *(ushort4*)(Wcbf + base) = ob;
}

// ---------------------------------------------------------------------------
// k_pack: bit-pack 3 adjacency matrices (f32 0/1 -> 1 bit), permuted layout:
// byte for k-chunk j (k in [8j,8j+8)) of row r lands at r*512 + (j&7)*64 + (j>>3),
// so k_gat thread (r,c8) reads step ks at byte r*512 + c8*64 + ks.
// One wave per row; 3*4096 rows; 4 waves/block -> 3072 blocks.
// ---------------------------------------------------------------------------
__global__ __launch_bounds__(256) void k_pack(
    const float* __restrict__ gene_adj, const float* __restrict__ cell_adj,
    const float* __restrict__ gc_adj,   u64* __restrict__ packbits)
{
  int t = threadIdx.x, wid = t>>6, lane = t&63;
  int gw = blockIdx.x*4 + wid;          // 0..12287
  int mat = gw >> 12;
  int row = gw & 4095;
  const float* src = (mat==0) ? gene_adj : (mat==1) ? cell_adj : gc_adj;
  u64* dst = packbits + (size_t)mat*262144 + (size_t)row*64;

  const int myc = lane >> 3;            // which byte of the ballot this lane wants
  const int mysel = lane & 7;           // which s-subrange this lane accumulates
  u64 acc = 0;
  for(int s = 0; s < 64; s++){
    float f = src[(size_t)row*NGC + s*64 + lane];
    u64 bal = __ballot(f != 0.0f);
    u64 part = ((bal >> (myc*8)) & 0xFFull) << (8*(s & 7));
    acc |= ((s >> 3) == mysel) ? part : 0;
  }
  dst[lane] = acc;
}

// ---------------------------------------------------------------------------
// k_bitTT: transpose gc bits -> bitsT (both in permuted layout).
// One wave per 64x64-bit tile; 4096 tiles; 4 waves/block -> 1024 blocks.
// In-wave 64x64 bit transpose via 6 shuffle steps.
// ---------------------------------------------------------------------------
__global__ __launch_bounds__(256) void k_bitTT(
    const uint8_t* __restrict__ gcbits, uint8_t* __restrict__ bitsT)
{
  int t = threadIdx.x, wid = t>>6, lane = t&63;
  int id = blockIdx.x*4 + wid;          // 0..4095
  int G = id & 63, C = id >> 6;

  // load row (64G+lane), cols [64C, 64C+64) -> x (bit c' = gc(64G+lane, 64C+c'))
  u64 x = 0;
  const uint8_t* srcp = gcbits + (size_t)(64*G + lane)*512 + C;
  #pragma unroll
  for(int d = 0; d < 8; d++)
    x |= ((u64)srcp[d*64]) << (8*d);

  // 6-step block-swap transpose: after, lane c' holds bit g' = gc(64G+g',64C+c')
  const u64 M1  = 0xAAAAAAAAAAAAAAAAull;
  const u64 M2  = 0xCCCCCCCCCCCCCCCCull;
  const u64 M4  = 0xF0F0F0F0F0F0F0F0ull;
  const u64 M8  = 0xFF00FF00FF00FF00ull;
  const u64 M16 = 0xFFFF0000FFFF0000ull;
  const u64 M32 = 0xFFFFFFFF00000000ull;
  #define TSTEP(S, M) { u64 y = shfl_xor64(x, S); \
    x = (lane & S) ? ((x & (M)) | ((y >> S) & ~(M))) \
                   : ((x & ~(M)) | ((y << S) & (M))); }
  TSTEP(32, M32) TSTEP(16, M16) TSTEP(8, M8)
  TSTEP(4,  M4)  TSTEP(2,  M2)  TSTEP(1, M1)
  #undef TSTEP

  // store bitsT row (64C+lane), g-chunk bytes at d'*64 + G
  uint8_t* dstp = bitsT + (size_t)(64*C + lane)*512 + G;
  #pragma unroll
  for(int d = 0; d < 8; d++)
    dstp[d*64] = (uint8_t)(x >> (8*d));
}

// ---------------------------------------------------------------------------
// k_hgemm: h = x @ W.T  (f32 x in -> bf16 staged, f32 h out + bf16 hT out)
// grid (64 row-tiles, 2 sides), 512 threads (8 waves). BM=64, BK=64, N=256.
// ---------------------------------------------------------------------------
__global__ __launch_bounds__(512) void k_hgemm(
    const float* __restrict__ xg, const float* __restrict__ xc,
    const u16* __restrict__ Wg, const u16* __restrict__ Wc,
    float* __restrict__ hg, float* __restrict__ hc,
    u16* __restrict__ hTg, u16* __restrict__ hTc)
{
  const int side = blockIdx.y;
  const float* x = side ? xc : xg;
  const u16* W = side ? Wc : Wg;
  float* h  = side ? hc : hg;
  u16*  hT  = side ? hTc : hTg;
  const int r0 = blockIdx.x * 64;
  const int t = threadIdx.x;
  const int wid = t >> 6, lane = t & 63;
  const int lrow = lane & 15, lhi = lane >> 4;

  __shared__ __align__(16) char smem[32768];

  f32x4 acc[4][2];
  const f32x4 z4 = {0.f,0.f,0.f,0.f};
  #pragma unroll
  for(int i=0;i<4;i++){ acc[i][0]=z4; acc[i][1]=z4; }

  const int r = t >> 3, c8 = t & 7;
  for(int k0 = 0; k0 < FIN; k0 += 64){
    const float* xp = x + (size_t)(r0 + r)*FIN + k0 + c8*8;
    float4 xa = *(const float4*)xp;
    float4 xb = *(const float4*)(xp + 4);
    short8 xv;
    xv[0]=(short)f2bf(xa.x); xv[1]=(short)f2bf(xa.y);
    xv[2]=(short)f2bf(xa.z); xv[3]=(short)f2bf(xa.w);
    xv[4]=(short)f2bf(xb.x); xv[5]=(short)f2bf(xb.y);
    xv[6]=(short)f2bf(xb.z); xv[7]=(short)f2bf(xb.w);
    int wbyte = r*128 + (((c8 ^ (r & 7)) & 7) << 4);
    *(short8*)(smem + wbyte) = xv;
    __syncthreads();
    #pragma unroll
    for(int ksub = 0; ksub < 2; ksub++){
      short8 b[2];
      #pragma unroll
      for(int nf=0; nf<2; nf++){
        int n = wid*32 + nf*16 + lrow;
        b[nf] = *(const short8*)(W + (size_t)n*FIN + k0 + ksub*32 + lhi*8);
      }
      #pragma unroll
      for(int mf=0; mf<4; mf++){
        int row = mf*16 + lrow;
        int g = ksub*4 + lhi;
        short8 a = *(const short8*)(smem + row*128 + (((g ^ (row & 7)) & 7) << 4));
        #pragma unroll
        for(int nf=0; nf<2; nf++)
          acc[mf][nf] = __builtin_amdgcn_mfma_f32_16x16x32_bf16(a, b[nf], acc[mf][nf], 0,0,0);
      }
    }
    __syncthreads();
  }
  // write h (f32) and stage bf16 transpose in LDS
  #pragma unroll
  for(int mf=0; mf<4; mf++){
    #pragma unroll
    for(int nf=0; nf<2; nf++){
      int col = wid*32 + nf*16 + lrow;
      #pragma unroll
      for(int j=0;j<4;j++){
        int row = mf*16 + lhi*4 + j;
        float v = acc[mf][nf][j];
        h[(size_t)(r0+row)*DD + col] = v;
        int byte_ = col*128 + (((row*2) ^ ((col & 7)<<4)));
        *(u16*)(smem + byte_) = f2bf(v);
      }
    }
  }
  __syncthreads();
  { // coalesced hT store: thread -> (n = t>>1, half = t&1)
    int n = t >> 1, half = t & 1;
    #pragma unroll
    for(int gi=0; gi<4; gi++){
      int g = half*4 + gi;
      int byte_ = n*128 + (((g ^ (n & 7)) & 7) << 4);
      short8 v = *(const short8*)(smem + byte_);
      *(short8*)(hT + (size_t)n*NGC + r0 + g*8) = v;
    }
  }
}

// ---------------------------------------------------------------------------
// k_svec: per-row dot products with attention vectors + gate sigmoid.
// sbuf layout (each 4096 f32):
// 0 s1gg 1 s2gg 2 s1gc 3 s2cg 4 gam_g 5 s1cc 6 s2cc 7 s2gc 8 s1cg 9 gam_c
// ---------------------------------------------------------------------------
__global__ __launch_bounds__(256) void k_svec(
    const float* __restrict__ hg, const float* __restrict__ hc,
    const float* __restrict__ a_gg, const float* __restrict__ a_gc,
    const float* __restrict__ a_cc, const float* __restrict__ a_cg,
    const float* __restrict__ gw_g, const float* __restrict__ gb_g,
    const float* __restrict__ gw_c, const float* __restrict__ gb_c,
    float* __restrict__ sbuf)
{
  int t = threadIdx.x, wid = t>>6, lane = t&63;
  int idx = blockIdx.x * 4 + wid;          // 0..8191
  int side = idx >> 12;
  int row  = idx & 4095;
  const float* h = (side ? hc : hg) + (size_t)row*DD;
  const float* v0 = (side ? a_cc : a_gg);        // same-type s1 half
  const float* v1 = (side ? a_cc : a_gg) + DD;   // same-type s2 half
  const float* v2 = (side ? a_cg : a_gc);        // cross s1 (this node as src)
  const float* v3 = (side ? a_gc : a_cg) + DD;   // cross s2 (this node as dst)
  const float* gw = side ? gw_c : gw_g;
  float bias = (side ? gb_c : gb_g)[0];

  float4 hv = *(const float4*)(h + lane*4);
  float4 w0 = *(const float4*)(v0 + lane*4);
  float4 w1 = *(const float4*)(v1 + lane*4);
  float4 w2 = *(const float4*)(v2 + lane*4);
  float4 w3 = *(const float4*)(v3 + lane*4);
  float4 w4 = *(const float4*)(gw + lane*4);

  float d0 = hv.x*w0.x + hv.y*w0.y + hv.z*w0.z + hv.w*w0.w;
  float d1 = hv.x*w1.x + hv.y*w1.y + hv.z*w1.z + hv.w*w1.w;
  float d2 = hv.x*w2.x + hv.y*w2.y + hv.z*w2.z + hv.w*w2.w;
  float d3 = hv.x*w3.x + hv.y*w3.y + hv.z*w3.z + hv.w*w3.w;
  float d4 = hv.x*w4.x + hv.y*w4.y + hv.z*w4.z + hv.w*w4.w;
  #pragma unroll
  for(int s=1;s<64;s<<=1){
    d0 += __shfl_xor(d0, s); d1 += __shfl_xor(d1, s); d2 += __shfl_xor(d2, s);
    d3 += __shfl_xor(d3, s); d4 += __shfl_xor(d4, s);
  }
  if(lane == 0){
    float gam = 1.f/(1.f + __expf(-(d4 + bias)));
    if(side == 0){
      sbuf[0*4096+row]=d0; sbuf[1*4096+row]=d1; sbuf[2*4096+row]=d2;
      sbuf[3*4096+row]=d3; sbuf[4*4096+row]=gam;
    } else {
      sbuf[5*4096+row]=d0; sbuf[6*4096+row]=d1; sbuf[8*4096+row]=d2;
      sbuf[7*4096+row]=d3; sbuf[9*4096+row]=gam;
    }
  }
}

// ---------------------------------------------------------------------------
// k_max: global max of the 4 "s2" arrays (one wave each). grid 1 x 256thr.
// ---------------------------------------------------------------------------
__global__ __launch_bounds__(256) void k_max(const float* __restrict__ sbuf,
                                             float* __restrict__ mx)
{
  int t = threadIdx.x, wid = t>>6, lane = t&63;
  const int offs[4] = {1,7,6,3};  // s2gg, s2gc(cell), s2cc, s2cg(gene)
  const float* a = sbuf + offs[wid]*4096;
  float m = -1e30f;
  for(int i = lane; i < 4096; i += 64) m = fmaxf(m, a[i]);
  #pragma unroll
  for(int s=1;s<64;s<<=1) m = fmaxf(m, __shfl_xor(m, s));
  if(lane==0) mx[wid] = m;
}

// ---------------------------------------------------------------------------
// k_gat: one masked-softmax attention block per blockIdx.y mode.
// grid (64 row-tiles, 4 modes), 512 threads (8 waves).
// All adjacency via packed bits (L2-resident); s2 staged in LDS.
// m_i = leaky(s1_i + max_j s2_j) upper-bounds all logits -> no online rescale.
// ---------------------------------------------------------------------------
__global__ __launch_bounds__(512) void k_gat(
    const float* __restrict__ sbuf, const float* __restrict__ mx,
    const uint8_t* __restrict__ packbits, const uint8_t* __restrict__ bitsT,
    const u16* __restrict__ hTg, const u16* __restrict__ hTc,
    float* __restrict__ blk)
{
  const int mode = blockIdx.y;
  const float* s1; const float* s2; const uint8_t* bits;
  const u16* vT; float* outp;
  if(mode == 0){ s1 = sbuf+0*4096; s2 = sbuf+1*4096; bits = packbits;           vT = hTg; outp = blk; }
  else if(mode == 1){ s1 = sbuf+2*4096; s2 = sbuf+7*4096; bits = packbits + 4194304; vT = hTc; outp = blk + 1048576; }
  else if(mode == 2){ s1 = sbuf+5*4096; s2 = sbuf+6*4096; bits = packbits + 2097152; vT = hTc; outp = blk + 2097152; }
  else { s1 = sbuf+8*4096; s2 = sbuf+3*4096; bits = bitsT; vT = hTg; outp = blk + 3145728; }

  const float maxs2 = mx[mode];
  const int r0 = blockIdx.x * 64;
  const int t = threadIdx.x;
  const int wid = t>>6, lane = t&63, lrow = lane&15, lhi = lane>>4;
  const int r = t>>3, c8 = t&7;
  const int srow = r0 + r;

  __shared__ __align__(16) char psmem[8192];   // P tile [64][64] bf16, swizzled
  __shared__ float s2_lds[4096];
  __shared__ float zbuf[64];

  // stage the full s2 row (16KB) into LDS
  {
    const float4* s2v4 = (const float4*)s2;
    float4* d4 = (float4*)s2_lds;
    d4[t] = s2v4[t];
    d4[t + 512] = s2v4[t + 512];
  }

  const float s1v = s1[srow];
  const float m = lk(s1v + maxs2);
  float zacc = 0.f;
  const f32x4 z4 = {0.f,0.f,0.f,0.f};
  f32x4 acc[4][2];
  #pragma unroll
  for(int i=0;i<4;i++){ acc[i][0]=z4; acc[i][1]=z4; }
  const int n0 = wid*32;
  const uint8_t* brow = bits + (size_t)srow*512 + c8*64;

  __syncthreads();   // s2_lds ready

  // prefetch first bits byte
  u32 ob = brow[0];

  for(int ks = 0; ks < 64; ks++){
    const int k0 = ks*64;
    u32 obc = ob;
    if(ks < 63) ob = brow[ks + 1];
    // ---- p generation (s2 from LDS, mask from bits) ----
    const float* s2p = s2_lds + k0 + c8*8;
    float4 ca = *(const float4*)s2p;
    float4 cb = *(const float4*)(s2p + 4);
    float s2v[8] = {ca.x,ca.y,ca.z,ca.w,cb.x,cb.y,cb.z,cb.w};
    short8 pw;
    #pragma unroll
    for(int j=0;j<8;j++){
      float e = __expf(lk(s1v + s2v[j]) - m);
      float p = ((obc>>j)&1u) ? e : 0.0f;
      zacc += p;
      pw[j] = (short)f2bf(p);
    }
    int wbyte = r*128 + (((c8 ^ (r&7)) & 7) << 4);
    *(short8*)(psmem + wbyte) = pw;
    __syncthreads();
    // ---- MFMA ----
    #pragma unroll
    for(int ksub=0; ksub<2; ksub++){
      short8 b[2];
      #pragma unroll
      for(int nf=0; nf<2; nf++){
        int n = n0 + nf*16 + lrow;
        b[nf] = *(const short8*)(vT + (size_t)n*NGC + k0 + ksub*32 + lhi*8);
      }
      #pragma unroll
      for(int mf=0; mf<4; mf++){
        int row = mf*16 + lrow;
        int g = ksub*4 + lhi;
        short8 a = *(const short8*)(psmem + row*128 + (((g ^ (row&7)) & 7) << 4));
        #pragma unroll
        for(int nf=0; nf<2; nf++)
          acc[mf][nf] = __builtin_amdgcn_mfma_f32_16x16x32_bf16(a, b[nf], acc[mf][nf], 0,0,0);
      }
    }
    __syncthreads();
  }
  // ---- Z reduction (8 threads per row are adjacent lanes) ----
  float z = zacc;
  z += __shfl_xor(z, 1);
  z += __shfl_xor(z, 2);
  z += __shfl_xor(z, 4);
  if(c8 == 0) zbuf[r] = z;
  __syncthreads();
  // ---- normalize + store ----
  #pragma unroll
  for(int mf=0; mf<4; mf++){
    #pragma unroll
    for(int j=0;j<4;j++){
      int row = mf*16 + lhi*4 + j;
      float rz = 1.f / fmaxf(zbuf[row], 1e-30f);
      #pragma unroll
      for(int nf=0; nf<2; nf++){
        int col = n0 + nf*16 + lrow;
        outp[(size_t)(r0+row)*DD + col] = acc[mf][nf][j] * rz;
      }
    }
  }
}

// ---------------------------------------------------------------------------
// k_epi: out = leaky(h + same + gamma*cross) for both sides.
// ---------------------------------------------------------------------------
__global__ __launch_bounds__(256) void k_epi(
    const float* __restrict__ hg, const float* __restrict__ hc,
    const float* __restrict__ blk, const float* __restrict__ sbuf,
    float* __restrict__ out)
{
  int i = blockIdx.x*256 + threadIdx.x;
  int base = i*4;
  int row = base >> 8;
  float gg = sbuf[4*4096 + row];
  float4 h4 = *(const float4*)(hg + base);
  float4 a4 = *(const float4*)(blk + base);
  float4 b4 = *(const float4*)(blk + 1048576 + base);
  float4 o;
  o.x = lk(h4.x + a4.x + gg*b4.x);
  o.y = lk(h4.y + a4.y + gg*b4.y);
  o.z = lk(h4.z + a4.z + gg*b4.z);
  o.w = lk(h4.w + a4.w + gg*b4.w);
  *(float4*)(out + base) = o;

  float gc = sbuf[9*4096 + row];
  float4 h4c = *(const float4*)(hc + base);
  float4 c4 = *(const float4*)(blk + 2097152 + base);
  float4 d4 = *(const float4*)(blk + 3145728 + base);
  float4 o2;
  o2.x = lk(h4c.x + c4.x + gc*d4.x);
  o2.y = lk(h4c.y + c4.y + gc*d4.y);
  o2.z = lk(h4c.z + c4.z + gc*d4.z);
  o2.w = lk(h4c.w + c4.w + gc*d4.w);
  *(float4*)(out + 1048576 + base) = o2;
}

// ---------------------------------------------------------------------------
extern "C" void kernel_launch(void* const* d_in, const int* in_sizes, int n_in,
                              void* d_out, int out_size, void* d_ws, size_t ws_size,
                              hipStream_t stream)
{
  const float* gene_x   = (const float*)d_in[0];
  const float* cell_x   = (const float*)d_in[1];
  const float* gene_adj = (const float*)d_in[2];
  const float* cell_adj = (const float*)d_in[3];
  const float* gc_adj   = (const float*)d_in[4];
  const float* Wg       = (const float*)d_in[5];
  const float* Wc       = (const float*)d_in[6];
  const float* a_gg     = (const float*)d_in[7];
  const float* a_gc     = (const float*)d_in[8];
  const float* a_cc     = (const float*)d_in[9];
  const float* a_cg     = (const float*)d_in[10];
  const float* gw_g     = (const float*)d_in[11];
  const float* gb_g     = (const float*)d_in[12];
  const float* gw_c     = (const float*)d_in[13];
  const float* gb_c     = (const float*)d_in[14];

  char* ws = (char*)d_ws;
  float* hg   = (float*)(ws);
  float* hc   = (float*)(ws + (4u<<20));
  u16*   hTg  = (u16*)  (ws + (8u<<20));
  u16*   hTc  = (u16*)  (ws + (10u<<20));
  float* sbuf = (float*)(ws + (12u<<20));
  float* mx   = (float*)(ws + (12u<<20) + (256u<<10));
  uint8_t* bitsT = (uint8_t*)(ws + (13u<<20));   // 2MB
  u16*   Wgbf = (u16*)  (ws + (15u<<20));
  u16*   Wcbf = (u16*)  (ws + (15u<<20) + (512u<<10));
  float* blk  = (float*)(ws + (16u<<20));        // 16MB
  u64*   packbits = (u64*)(ws + (32u<<20));      // 6MB: gene@+0, cell@+2MB, gc@+4MB

  k_wcvt<<<dim3(128), 256, 0, stream>>>(Wg, Wc, Wgbf, Wcbf);
  k_pack<<<dim3(3072), 256, 0, stream>>>(gene_adj, cell_adj, gc_adj, packbits);
  k_bitTT<<<dim3(1024), 256, 0, stream>>>((const uint8_t*)packbits + 4194304, bitsT);
  k_hgemm<<<dim3(64,2), 512, 0, stream>>>(gene_x, cell_x, Wgbf, Wcbf, hg, hc, hTg, hTc);
  k_svec<<<dim3(2048), 256, 0, stream>>>(hg, hc, a_gg, a_gc, a_cc, a_cg,
                                         gw_g, gb_g, gw_c, gb_c, sbuf);
  k_max<<<dim3(1), 256, 0, stream>>>(sbuf, mx);
  k_gat<<<dim3(64,4), 512, 0, stream>>>(sbuf, mx, (const uint8_t*)packbits,
                                        bitsT, hTg, hTc, blk);
  k_epi<<<dim3(1024), 256, 0, stream>>>(hg, hc, blk, sbuf, (float*)d_out);
}